// Round 1
// baseline (17797.194 us; speedup 1.0000x reference)
//
#include <hip/hip_runtime.h>
#include <hip/hip_fp16.h>

#define T_LEN 512
#define DDIM 512
#define HDIM 512
#define BATCH 64
#define NWG_DIR 64      // workgroups per direction
#define UNITS_PER_WG 8  // hidden units per wg -> 32 gate rows

typedef _Float16 v8h __attribute__((ext_vector_type(8)));
typedef float v4f __attribute__((ext_vector_type(4)));

__device__ __forceinline__ float sigf(float x) { return 1.0f / (1.0f + __expf(-x)); }
__device__ __forceinline__ float tanh_fast(float x) { return 2.0f / (1.0f + __expf(-2.0f * x)) - 1.0f; }

// ws layout:
//   [0]      : barrier counter fw (u32)
//   [256]    : barrier counter bw (u32)
//   [4096]   : h double buffers: f16 [dir(2)][phase(2)][BATCH][HDIM] = 262144 B
#define WS_HB_OFF 4096
#define WS_NEED (WS_HB_OFF + 4 * BATCH * HDIM * 2)

__global__ void __launch_bounds__(256, 1) bilstm_kernel(
    const float* __restrict__ x,
    const float* __restrict__ Wih_fw, const float* __restrict__ Whh_fw,
    const float* __restrict__ Wih_bw, const float* __restrict__ Whh_bw,
    float* __restrict__ out, unsigned char* __restrict__ ws)
{
  const int wg   = blockIdx.x;
  const int dir  = wg >> 6;       // 0 = fw, 1 = bw
  const int sub  = wg & 63;       // which unit-group
  const int tid  = threadIdx.x;
  const int wave = tid >> 6;
  const int lane = tid & 63;
  const int n    = lane & 15;     // MFMA "low" index
  const int q    = lane >> 4;     // MFMA quad
  const int u0   = sub * UNITS_PER_WG;

  // Weights, f16, layout [kc(32)][q(4)][r(32)][8] ; element (kc,q,r,j) holds
  // W_row(r)[ (kc&15)*32 + q*8 + j ], kc<16 -> Wih, kc>=16 -> Whh.
  // r = gate*8 + uu  (gate order i,f,g,o), row R = gate*HDIM + u0 + uu.
  __shared__ _Float16 Wlds[32 * 4 * 32 * 8];  // 64 KiB

  const float* __restrict__ Wih = dir ? Wih_bw : Wih_fw;
  const float* __restrict__ Whh = dir ? Whh_bw : Whh_fw;

  for (int idx = tid; idx < 32768; idx += 256) {
    const int j  = idx & 7;
    const int r  = (idx >> 3) & 31;
    const int qq = (idx >> 8) & 3;
    const int kc = idx >> 10;
    const int k  = (kc & 15) * 32 + qq * 8 + j;
    const int gate = r >> 3, uu = r & 7;
    const int R = gate * HDIM + u0 + uu;
    const float wv = (kc < 16) ? Wih[(size_t)R * DDIM + k] : Whh[(size_t)R * HDIM + k];
    Wlds[idx] = (_Float16)wv;
  }
  __syncthreads();

  _Float16* hb = (_Float16*)(ws + WS_HB_OFF) + (size_t)dir * 2 * (BATCH * HDIM);
  unsigned int* ctr = (unsigned int*)(ws + dir * 256);

  float cr[4] = {0.f, 0.f, 0.f, 0.f};  // c state (valid on lanes with n<8)
  const int bload = wave * 16 + n;     // batch row this lane loads for A-frags

  for (int t = 0; t < T_LEN; ++t) {
    const int tx = dir ? (T_LEN - 1 - t) : t;
    const float*    xrow = x + ((size_t)bload * T_LEN + tx) * DDIM;
    const _Float16* hrow = hb + (t & 1) * (BATCH * HDIM) + bload * HDIM;

    v4f acc0 = {0.f, 0.f, 0.f, 0.f};  // rows 0..15  : i (n<8) / f (n>=8)
    v4f acc1 = {0.f, 0.f, 0.f, 0.f};  // rows 16..31 : g (n<8) / o (n>=8)

    // x part: K chunks 0..15
    #pragma unroll
    for (int kc = 0; kc < 16; ++kc) {
      const float4 lo = *(const float4*)(xrow + kc * 32 + q * 8);
      const float4 hi = *(const float4*)(xrow + kc * 32 + q * 8 + 4);
      v8h a;
      a[0] = (_Float16)lo.x; a[1] = (_Float16)lo.y; a[2] = (_Float16)lo.z; a[3] = (_Float16)lo.w;
      a[4] = (_Float16)hi.x; a[5] = (_Float16)hi.y; a[6] = (_Float16)hi.z; a[7] = (_Float16)hi.w;
      const v8h b0 = *(const v8h*)(&Wlds[(((kc * 4 + q) * 32) + n) * 8]);
      const v8h b1 = *(const v8h*)(&Wlds[(((kc * 4 + q) * 32) + 16 + n) * 8]);
      acc0 = __builtin_amdgcn_mfma_f32_16x16x32_f16(a, b0, acc0, 0, 0, 0);
      acc1 = __builtin_amdgcn_mfma_f32_16x16x32_f16(a, b1, acc1, 0, 0, 0);
    }
    // h part: K chunks 16..31
    #pragma unroll
    for (int kc = 16; kc < 32; ++kc) {
      const v8h a = *(const v8h*)(hrow + (kc - 16) * 32 + q * 8);
      const v8h b0 = *(const v8h*)(&Wlds[(((kc * 4 + q) * 32) + n) * 8]);
      const v8h b1 = *(const v8h*)(&Wlds[(((kc * 4 + q) * 32) + 16 + n) * 8]);
      acc0 = __builtin_amdgcn_mfma_f32_16x16x32_f16(a, b0, acc0, 0, 0, 0);
      acc1 = __builtin_amdgcn_mfma_f32_16x16x32_f16(a, b1, acc1, 0, 0, 0);
    }

    // pointwise LSTM cell update.
    // D layout: batch m = wave*16 + q*4 + r ; col = n.
    // lane n<8 owns unit u0+n: acc0 = i, acc1 = g ; partner lane (n+8): f, o.
    float hv[4];
    #pragma unroll
    for (int r = 0; r < 4; ++r) {
      const float iv = acc0[r];
      const float gv = acc1[r];
      const float fv = __shfl_xor(iv, 8);
      const float ov = __shfl_xor(gv, 8);
      const float cn = sigf(fv) * cr[r] + sigf(iv) * tanh_fast(gv);
      cr[r] = cn;
      hv[r] = sigf(ov) * tanh_fast(cn);
    }
    _Float16* hwrite = hb + ((t + 1) & 1) * (BATCH * HDIM);
    if (n < 8) {
      const int unit = u0 + n;
      #pragma unroll
      for (int r = 0; r < 4; ++r) {
        const int bb = wave * 16 + q * 4 + r;
        hwrite[bb * HDIM + unit] = (_Float16)hv[r];
        atomicAdd(out + ((size_t)tx * BATCH + bb) * HDIM + unit, hv[r]);
      }
    }

    // device-scope barrier over this direction's 64 workgroups
    __threadfence();
    __syncthreads();
    if (tid == 0) {
      __hip_atomic_fetch_add(ctr, 1u, __ATOMIC_ACQ_REL, __HIP_MEMORY_SCOPE_AGENT);
      const unsigned int target = (unsigned int)NWG_DIR * (unsigned int)(t + 1);
      while (__hip_atomic_load(ctr, __ATOMIC_ACQUIRE, __HIP_MEMORY_SCOPE_AGENT) < target) {
        __builtin_amdgcn_s_sleep(1);
      }
    }
    __syncthreads();
    __threadfence();
  }
}

extern "C" void kernel_launch(void* const* d_in, const int* in_sizes, int n_in,
                              void* d_out, int out_size, void* d_ws, size_t ws_size,
                              hipStream_t stream) {
  const float* x      = (const float*)d_in[0];
  const float* Wih_fw = (const float*)d_in[1];
  const float* Whh_fw = (const float*)d_in[2];
  const float* Wih_bw = (const float*)d_in[3];
  const float* Whh_bw = (const float*)d_in[4];
  float* out = (float*)d_out;
  unsigned char* ws = (unsigned char*)d_ws;

  // d_out / d_ws are poisoned 0xAA before every launch: zero what we use.
  hipMemsetAsync(d_out, 0, (size_t)out_size * sizeof(float), stream);
  hipMemsetAsync(d_ws, 0, (size_t)WS_NEED, stream);

  void* args[] = {(void*)&x, (void*)&Wih_fw, (void*)&Whh_fw, (void*)&Wih_bw,
                  (void*)&Whh_bw, (void*)&out, (void*)&ws};
  hipLaunchCooperativeKernel((const void*)bilstm_kernel, dim3(2 * NWG_DIR),
                             dim3(256), args, 0, stream);
}

// Round 2
// 6501.593 us; speedup vs baseline: 2.7374x; 2.7374x over previous
//
#include <hip/hip_runtime.h>
#include <hip/hip_fp16.h>

#define T_LEN 512
#define DDIM 512
#define HDIM 512
#define BATCH 64
#define NWG_DIR 64      // workgroups per direction
#define UNITS_PER_WG 8  // hidden units per wg -> 32 gate rows (interleaved [unit][gate])

typedef _Float16 v8h __attribute__((ext_vector_type(8)));
typedef float v4f __attribute__((ext_vector_type(4)));

__device__ __forceinline__ float sigf(float x) { return 1.0f / (1.0f + __expf(-x)); }
__device__ __forceinline__ float tanh_fast(float x) { return 2.0f / (1.0f + __expf(-2.0f * x)) - 1.0f; }

// ws layout:
//   [0]      : barrier counter fw (u32)        [256]: barrier counter bw
//   [4096]   : h double buffers: f16 [dir(2)][phase(2)][BATCH][HDIM] = 256 KiB
// h storage uses a per-WG unit permutation: within owner-WG su, stored pos
// loc = q*2 + pair holds true unit su*8 + pair*4 + q  (lets one lane pack its
// two h outputs (units u0+q, u0+4+q) into a single u32 sc1 store).
#define WS_HB_OFF 4096
#define WS_NEED (WS_HB_OFF + 2 * 2 * BATCH * HDIM * 2)

__global__ void __launch_bounds__(256, 1) bilstm_kernel(
    const float* __restrict__ x,
    const float* __restrict__ Wih_fw, const float* __restrict__ Whh_fw,
    const float* __restrict__ Wih_bw, const float* __restrict__ Whh_bw,
    float* __restrict__ out, unsigned char* __restrict__ ws)
{
  const int wg   = blockIdx.x;
  const int dir  = wg >> 6;       // 0 = fw, 1 = bw
  const int sub  = wg & 63;
  const int tid  = threadIdx.x;
  const int w    = tid >> 6;      // wave -> batch block (16 batches)
  const int lane = tid & 63;
  const int n    = lane & 15;     // MFMA col (batch within block) / A-row
  const int q    = lane >> 4;     // MFMA quad
  const int u0   = sub * UNITS_PER_WG;

  // Weights f16, layout [kc(32)][q(4)][r(32)][8]; r = tile*16 + m where the
  // 16-row A-tile has m = ulocal*4 + gate (ulocal = tile*4 + (m>>2)).
  // kc<16: Wih columns (no permutation). kc>=16: Whh columns permuted to match
  // the stored-h unit order (see WS comment).
  __shared__ _Float16 Wlds[32 * 4 * 32 * 8];  // 64 KiB

  const float* __restrict__ Wih = dir ? Wih_bw : Wih_fw;
  const float* __restrict__ Whh = dir ? Whh_bw : Whh_fw;

  for (int idx = tid; idx < 32768; idx += 256) {
    const int j    = idx & 7;
    const int r    = (idx >> 3) & 31;
    const int qq   = (idx >> 8) & 3;
    const int kc   = idx >> 10;
    const int tile = r >> 4, m = r & 15;
    const int unit = u0 + tile * 4 + (m >> 2);
    const int gate = m & 3;                      // i,f,g,o
    const int R    = gate * HDIM + unit;
    float wv;
    if (kc < 16) {
      const int k = kc * 32 + qq * 8 + j;
      wv = Wih[(size_t)R * DDIM + k];
    } else {
      const int p = (kc - 16) * 32 + qq * 8 + j;               // stored-h pos
      const int U = (p >> 3) * 8 + (p & 1) * 4 + ((p >> 1) & 3);  // true unit
      wv = Whh[(size_t)R * HDIM + U];
    }
    Wlds[idx] = (_Float16)wv;
  }
  __syncthreads();

  _Float16* hb = (_Float16*)(ws + WS_HB_OFF) + (size_t)dir * 2 * (BATCH * HDIM);
  unsigned int* ctr = (unsigned int*)(ws + dir * 256);

  const int b = w * 16 + n;   // batch row this lane owns (B-frag col / output)
  float cA = 0.f, cB = 0.f;   // c-state: units u0+q and u0+4+q for batch b

  for (int t = 0; t < T_LEN; ++t) {
    const int tx = dir ? (T_LEN - 1 - t) : t;
    const float*    xrow = x + ((size_t)b * T_LEN + tx) * DDIM;
    const _Float16* hrow = hb + (t & 1) * (BATCH * HDIM) + b * HDIM;

    // Issue ALL h loads (device-coherent, L3-latency) up front so they fly
    // during the x-part MFMAs. 32 x 8B = 64 VGPRs.
    unsigned long long hu[32];
    #pragma unroll
    for (int kc = 0; kc < 16; ++kc) {
      const unsigned long long* hp =
          (const unsigned long long*)(hrow + kc * 32 + q * 8);
      hu[2 * kc]     = __hip_atomic_load(hp,     __ATOMIC_RELAXED, __HIP_MEMORY_SCOPE_AGENT);
      hu[2 * kc + 1] = __hip_atomic_load(hp + 1, __ATOMIC_RELAXED, __HIP_MEMORY_SCOPE_AGENT);
    }

    v4f acc0 = {0.f, 0.f, 0.f, 0.f};  // rows 0..15  : units u0+q,   gates 0..3
    v4f acc1 = {0.f, 0.f, 0.f, 0.f};  // rows 16..31 : units u0+4+q, gates 0..3

    // x part (K chunks 0..15): B-frag from global x (L2-resident), A from LDS.
    #pragma unroll
    for (int kc = 0; kc < 16; ++kc) {
      const float4 lo = *(const float4*)(xrow + kc * 32 + q * 8);
      const float4 hi = *(const float4*)(xrow + kc * 32 + q * 8 + 4);
      v8h bf;
      bf[0] = (_Float16)lo.x; bf[1] = (_Float16)lo.y; bf[2] = (_Float16)lo.z; bf[3] = (_Float16)lo.w;
      bf[4] = (_Float16)hi.x; bf[5] = (_Float16)hi.y; bf[6] = (_Float16)hi.z; bf[7] = (_Float16)hi.w;
      const v8h a0 = *(const v8h*)(&Wlds[(((kc * 4 + q) * 32) + n) * 8]);
      const v8h a1 = *(const v8h*)(&Wlds[(((kc * 4 + q) * 32) + 16 + n) * 8]);
      acc0 = __builtin_amdgcn_mfma_f32_16x16x32_f16(a0, bf, acc0, 0, 0, 0);
      acc1 = __builtin_amdgcn_mfma_f32_16x16x32_f16(a1, bf, acc1, 0, 0, 0);
    }
    // h part (K chunks 16..31)
    #pragma unroll
    for (int kc = 16; kc < 32; ++kc) {
      union { unsigned long long u[2]; v8h h; } cv;
      cv.u[0] = hu[2 * (kc - 16)];
      cv.u[1] = hu[2 * (kc - 16) + 1];
      const v8h a0 = *(const v8h*)(&Wlds[(((kc * 4 + q) * 32) + n) * 8]);
      const v8h a1 = *(const v8h*)(&Wlds[(((kc * 4 + q) * 32) + 16 + n) * 8]);
      acc0 = __builtin_amdgcn_mfma_f32_16x16x32_f16(a0, cv.h, acc0, 0, 0, 0);
      acc1 = __builtin_amdgcn_mfma_f32_16x16x32_f16(a1, cv.h, acc1, 0, 0, 0);
    }

    // Pointwise LSTM cell: all 4 gates of each unit are lane-local.
    cA = sigf(acc0[1]) * cA + sigf(acc0[0]) * tanh_fast(acc0[2]);
    const float hA = sigf(acc0[3]) * tanh_fast(cA);
    cB = sigf(acc1[1]) * cB + sigf(acc1[0]) * tanh_fast(acc1[2]);
    const float hB = sigf(acc1[3]) * tanh_fast(cB);

    // h exchange: one packed u32 device-coherent store per lane.
    union { _Float16 h[2]; unsigned int u; } pk;
    pk.h[0] = (_Float16)hA;  // stored pos q*2+0 <-> unit u0+q
    pk.h[1] = (_Float16)hB;  // stored pos q*2+1 <-> unit u0+4+q
    unsigned int* hw32 = (unsigned int*)(hb + ((t + 1) & 1) * (BATCH * HDIM));
    __hip_atomic_store(&hw32[b * 256 + (u0 >> 1) + q], pk.u,
                       __ATOMIC_RELAXED, __HIP_MEMORY_SCOPE_AGENT);

    // out accumulation (fw+bw): device-coherent atomics, never dirty L2.
    float* orow = out + ((size_t)tx * BATCH + b) * HDIM;
    __hip_atomic_fetch_add(orow + u0 + q,     hA, __ATOMIC_RELAXED, __HIP_MEMORY_SCOPE_AGENT);
    __hip_atomic_fetch_add(orow + u0 + 4 + q, hB, __ATOMIC_RELAXED, __HIP_MEMORY_SCOPE_AGENT);

    // Lightweight device barrier: no cache maintenance. sc1 ops serialize at
    // the IF coherence point; vmcnt(0) drain is the release.
    asm volatile("s_waitcnt vmcnt(0)" ::: "memory");
    __syncthreads();
    if (tid == 0) {
      __hip_atomic_fetch_add(ctr, 1u, __ATOMIC_RELAXED, __HIP_MEMORY_SCOPE_AGENT);
      const unsigned int target = (unsigned int)NWG_DIR * (unsigned int)(t + 1);
      while (__hip_atomic_load(ctr, __ATOMIC_RELAXED, __HIP_MEMORY_SCOPE_AGENT) < target) {
        __builtin_amdgcn_s_sleep(2);
      }
    }
    __syncthreads();
  }
}

extern "C" void kernel_launch(void* const* d_in, const int* in_sizes, int n_in,
                              void* d_out, int out_size, void* d_ws, size_t ws_size,
                              hipStream_t stream) {
  const float* x      = (const float*)d_in[0];
  const float* Wih_fw = (const float*)d_in[1];
  const float* Whh_fw = (const float*)d_in[2];
  const float* Wih_bw = (const float*)d_in[3];
  const float* Whh_bw = (const float*)d_in[4];
  float* out = (float*)d_out;
  unsigned char* ws = (unsigned char*)d_ws;

  hipMemsetAsync(d_out, 0, (size_t)out_size * sizeof(float), stream);
  hipMemsetAsync(d_ws, 0, (size_t)WS_NEED, stream);

  void* args[] = {(void*)&x, (void*)&Wih_fw, (void*)&Whh_fw, (void*)&Wih_bw,
                  (void*)&Whh_bw, (void*)&out, (void*)&ws};
  hipLaunchCooperativeKernel((const void*)bilstm_kernel, dim3(2 * NWG_DIR),
                             dim3(256), args, 0, stream);
}

// Round 3
// 5487.433 us; speedup vs baseline: 3.2433x; 1.1848x over previous
//
#include <hip/hip_runtime.h>
#include <hip/hip_fp16.h>

#define T_LEN 512
#define DDIM 512
#define HDIM 512
#define BATCH 64
#define NWG_DIR 64      // workgroups per direction
#define UNITS_PER_WG 8  // hidden units per wg -> 32 gate rows (interleaved [unit][gate])

typedef _Float16 v8h __attribute__((ext_vector_type(8)));
typedef float v4f __attribute__((ext_vector_type(4)));

__device__ __forceinline__ float sigf(float x) { return 1.0f / (1.0f + __expf(-x)); }
__device__ __forceinline__ float tanh_fast(float x) { return 2.0f / (1.0f + __expf(-2.0f * x)) - 1.0f; }

// ws layout:
//   [0 .. 8K)      : flags, u32 at (dir*64+sub)*64 bytes — monotonic step count
//   [16K .. 16K+256K) : h double buffers: f16 [dir(2)][phase(2)][BATCH][HDIM]
//   [272K ...)     : bw-direction output buffer (f32, 64 MB) when ws permits
// h storage unit permutation within owner-WG su: stored pos q*2+pair holds
// true unit su*8 + pair*4 + q (one packed u32 store per lane).
#define WS_HB_OFF 16384
#define WS_BWOUT_OFF (WS_HB_OFF + 2 * 2 * BATCH * HDIM * 2)
#define OUT_BYTES ((size_t)T_LEN * BATCH * HDIM * 4)
#define WS_NEED_BASE WS_BWOUT_OFF
#define WS_NEED_SPLIT (WS_BWOUT_OFF + OUT_BYTES)

__global__ void __launch_bounds__(256, 1) bilstm_kernel(
    const float* __restrict__ x,
    const float* __restrict__ Wih_fw, const float* __restrict__ Whh_fw,
    const float* __restrict__ Wih_bw, const float* __restrict__ Whh_bw,
    float* __restrict__ out, float* __restrict__ out_bw,
    unsigned char* __restrict__ ws, int split)
{
  const int wg   = blockIdx.x;
  const int dir  = wg >> 6;       // 0 = fw, 1 = bw
  const int sub  = wg & 63;
  const int tid  = threadIdx.x;
  const int w    = tid >> 6;      // wave -> batch block (16 batches)
  const int lane = tid & 63;
  const int n    = lane & 15;     // MFMA col (batch within block) / A-row
  const int q    = lane >> 4;     // MFMA quad
  const int u0   = sub * UNITS_PER_WG;

  // Weights f16, layout [kc(32)][q(4)][r(32)][8]; r = tile*16 + m, rows
  // interleaved m = ulocal*4 + gate. kc<16: Wih. kc>=16: Whh with columns
  // permuted to the stored-h unit order.
  __shared__ _Float16 Wlds[32 * 4 * 32 * 8];  // 64 KiB

  const float* __restrict__ Wih = dir ? Wih_bw : Wih_fw;
  const float* __restrict__ Whh = dir ? Whh_bw : Whh_fw;

  for (int idx = tid; idx < 32768; idx += 256) {
    const int j    = idx & 7;
    const int r    = (idx >> 3) & 31;
    const int qq   = (idx >> 8) & 3;
    const int kc   = idx >> 10;
    const int tile = r >> 4, m = r & 15;
    const int unit = u0 + tile * 4 + (m >> 2);
    const int gate = m & 3;                      // i,f,g,o
    const int R    = gate * HDIM + unit;
    float wv;
    if (kc < 16) {
      const int k = kc * 32 + qq * 8 + j;
      wv = Wih[(size_t)R * DDIM + k];
    } else {
      const int p = (kc - 16) * 32 + qq * 8 + j;                  // stored pos
      const int U = (p >> 3) * 8 + (p & 1) * 4 + ((p >> 1) & 3);  // true unit
      wv = Whh[(size_t)R * HDIM + U];
    }
    Wlds[idx] = (_Float16)wv;
  }
  __syncthreads();

  _Float16* hb = (_Float16*)(ws + WS_HB_OFF) + (size_t)dir * 2 * (BATCH * HDIM);
  unsigned int* flags = (unsigned int*)ws + (size_t)dir * 64 * 16;  // stride 16 u32 = 64 B
  unsigned int* myflag = flags + (size_t)sub * 16;
  const unsigned int* pollflag = flags + (size_t)(tid & 63) * 16;

  float* myout = dir ? out_bw : out;

  const int b = w * 16 + n;   // batch row this lane owns
  float cA = 0.f, cB = 0.f;   // c-state: units u0+q and u0+4+q for batch b

  for (int t = 0; t < T_LEN; ++t) {
    const int tx = dir ? (T_LEN - 1 - t) : t;
    const float*    xrow = x + ((size_t)b * T_LEN + tx) * DDIM;
    const _Float16* hrow = hb + (t & 1) * (BATCH * HDIM) + b * HDIM;

    v4f acc0 = {0.f, 0.f, 0.f, 0.f};  // units u0+q,   gates i,f,g,o
    v4f acc1 = {0.f, 0.f, 0.f, 0.f};  // units u0+4+q, gates i,f,g,o

    // ---- x phase: independent of h(t); runs before/while producers finish.
    #pragma unroll
    for (int kc = 0; kc < 16; ++kc) {
      const float4 lo = *(const float4*)(xrow + kc * 32 + q * 8);
      const float4 hi = *(const float4*)(xrow + kc * 32 + q * 8 + 4);
      v8h bf;
      bf[0] = (_Float16)lo.x; bf[1] = (_Float16)lo.y; bf[2] = (_Float16)lo.z; bf[3] = (_Float16)lo.w;
      bf[4] = (_Float16)hi.x; bf[5] = (_Float16)hi.y; bf[6] = (_Float16)hi.z; bf[7] = (_Float16)hi.w;
      const v8h a0 = *(const v8h*)(&Wlds[(((kc * 4 + q) * 32) + n) * 8]);
      const v8h a1 = *(const v8h*)(&Wlds[(((kc * 4 + q) * 32) + 16 + n) * 8]);
      acc0 = __builtin_amdgcn_mfma_f32_16x16x32_f16(a0, bf, acc0, 0, 0, 0);
      acc1 = __builtin_amdgcn_mfma_f32_16x16x32_f16(a1, bf, acc1, 0, 0, 0);
    }

    // ---- wait for all 64 producers of this dir to have finished step t-1.
    // Wave 0: lane i spins on flag i (64 distinct cachelines, no RMW).
    if (tid < 64) {
      while (__hip_atomic_load(pollflag, __ATOMIC_RELAXED,
                               __HIP_MEMORY_SCOPE_AGENT) < (unsigned int)t) {
      }
    }
    __syncthreads();

    // ---- h phase.
    unsigned long long hu[32];
    #pragma unroll
    for (int kc = 0; kc < 16; ++kc) {
      const unsigned long long* hp =
          (const unsigned long long*)(hrow + kc * 32 + q * 8);
      hu[2 * kc]     = __hip_atomic_load(hp,     __ATOMIC_RELAXED, __HIP_MEMORY_SCOPE_AGENT);
      hu[2 * kc + 1] = __hip_atomic_load(hp + 1, __ATOMIC_RELAXED, __HIP_MEMORY_SCOPE_AGENT);
    }
    #pragma unroll
    for (int kc = 16; kc < 32; ++kc) {
      union { unsigned long long u[2]; v8h h; } cv;
      cv.u[0] = hu[2 * (kc - 16)];
      cv.u[1] = hu[2 * (kc - 16) + 1];
      const v8h a0 = *(const v8h*)(&Wlds[(((kc * 4 + q) * 32) + n) * 8]);
      const v8h a1 = *(const v8h*)(&Wlds[(((kc * 4 + q) * 32) + 16 + n) * 8]);
      acc0 = __builtin_amdgcn_mfma_f32_16x16x32_f16(a0, cv.h, acc0, 0, 0, 0);
      acc1 = __builtin_amdgcn_mfma_f32_16x16x32_f16(a1, cv.h, acc1, 0, 0, 0);
    }

    // ---- pointwise LSTM cell: all 4 gates lane-local.
    cA = sigf(acc0[1]) * cA + sigf(acc0[0]) * tanh_fast(acc0[2]);
    const float hA = sigf(acc0[3]) * tanh_fast(cA);
    cB = sigf(acc1[1]) * cB + sigf(acc1[0]) * tanh_fast(acc1[2]);
    const float hB = sigf(acc1[3]) * tanh_fast(cB);

    // ---- output: plain L2 stores (split mode) or device atomics (fallback).
    float* orow = myout + ((size_t)tx * BATCH + b) * HDIM;
    if (split) {
      orow[u0 + q]     = hA;
      orow[u0 + 4 + q] = hB;
    } else {
      __hip_atomic_fetch_add(orow + u0 + q,     hA, __ATOMIC_RELAXED, __HIP_MEMORY_SCOPE_AGENT);
      __hip_atomic_fetch_add(orow + u0 + 4 + q, hB, __ATOMIC_RELAXED, __HIP_MEMORY_SCOPE_AGENT);
    }

    // ---- h exchange: one packed u32 device-coherent store per lane.
    union { _Float16 h[2]; unsigned int u; } pk;
    pk.h[0] = (_Float16)hA;  // stored pos q*2+0 <-> unit u0+q
    pk.h[1] = (_Float16)hB;  // stored pos q*2+1 <-> unit u0+4+q
    unsigned int* hw32 = (unsigned int*)(hb + ((t + 1) & 1) * (BATCH * HDIM));
    __hip_atomic_store(&hw32[b * 256 + (u0 >> 1) + q], pk.u,
                       __ATOMIC_RELAXED, __HIP_MEMORY_SCOPE_AGENT);

    // ---- publish: drain own stores, WG-sync, set own flag.
    asm volatile("s_waitcnt vmcnt(0)" ::: "memory");
    __syncthreads();
    if (tid == 0) {
      __hip_atomic_store(myflag, (unsigned int)(t + 1),
                         __ATOMIC_RELAXED, __HIP_MEMORY_SCOPE_AGENT);
    }
  }
}

__global__ void __launch_bounds__(256) add_kernel(float* __restrict__ out,
                                                  const float* __restrict__ addend) {
  const size_t i = ((size_t)blockIdx.x * 256 + threadIdx.x) * 4;
  float4 a = *(const float4*)(out + i);
  const float4 b = *(const float4*)(addend + i);
  a.x += b.x; a.y += b.y; a.z += b.z; a.w += b.w;
  *(float4*)(out + i) = a;
}

extern "C" void kernel_launch(void* const* d_in, const int* in_sizes, int n_in,
                              void* d_out, int out_size, void* d_ws, size_t ws_size,
                              hipStream_t stream) {
  const float* x      = (const float*)d_in[0];
  const float* Wih_fw = (const float*)d_in[1];
  const float* Whh_fw = (const float*)d_in[2];
  const float* Wih_bw = (const float*)d_in[3];
  const float* Whh_bw = (const float*)d_in[4];
  float* out = (float*)d_out;
  unsigned char* ws = (unsigned char*)d_ws;

  const int split = (ws_size >= (size_t)WS_NEED_SPLIT) ? 1 : 0;
  float* out_bw = split ? (float*)(ws + WS_BWOUT_OFF) : out;

  // flags + h buffers must start at 0 (ws is poisoned 0xAA before each call).
  hipMemsetAsync(d_ws, 0, (size_t)WS_NEED_BASE, stream);
  if (!split) {
    hipMemsetAsync(d_out, 0, (size_t)out_size * sizeof(float), stream);
  }

  void* args[] = {(void*)&x, (void*)&Wih_fw, (void*)&Whh_fw, (void*)&Wih_bw,
                  (void*)&Whh_bw, (void*)&out, (void*)&out_bw, (void*)&ws,
                  (void*)&split};
  hipLaunchCooperativeKernel((const void*)bilstm_kernel, dim3(2 * NWG_DIR),
                             dim3(256), args, 0, stream);

  if (split) {
    const int n4 = (int)(OUT_BYTES / 16);  // float4 count = 16777216/... 4194304
    add_kernel<<<dim3(n4 / 256), dim3(256), 0, stream>>>(out, out_bw);
  }
}